// Round 6
// baseline (556.216 us; speedup 1.0000x reference)
//
#include <hip/hip_runtime.h>
#include <stdint.h>

// ---------------------------------------------------------------------------
// Fused LSTM cell, round 6: LDS-free, barrier-free, 16 free-running waves/CU,
// manual 2-deep register prefetch for A (HBM fp32) and B (L2 bf16 fragments).
//  prep_w: unchanged (fragment-packed bf16 Bt in d_ws, K zero-padded).
//  lstm_main: 256 thr = 4 waves (2 wr x 2 wc), block tile 64 rows x 128
//  gate-cols, per-wave 32x64 (acc[2][4] = 32 VGPR). 12 fully-unrolled BK=32
//  chunks; all buffer indices [c&1] fold to constants after unroll.
//  Per chunk: cvt A(c) -> issue A(c+2) -> 8 MFMA on B(c) -> issue B(c+2).
//  No sync points anywhere; waves destagger naturally.
// ---------------------------------------------------------------------------

typedef short          bf16x8 __attribute__((ext_vector_type(8)));
typedef unsigned short u16x8  __attribute__((ext_vector_type(8)));
typedef float          f32x4  __attribute__((ext_vector_type(4)));
typedef unsigned int   u32x4  __attribute__((ext_vector_type(4)));

#define HDIM   256
#define INDIM  100
#define NROWS  131072

__device__ __forceinline__ float fexp(float x) {
  return __builtin_amdgcn_exp2f(x * 1.44269504088896340736f);
}
__device__ __forceinline__ float frcp(float x) { return __builtin_amdgcn_rcpf(x); }
__device__ __forceinline__ float sigm(float x) { return frcp(1.0f + fexp(-x)); }
__device__ __forceinline__ float tanh_fast(float x) {
  return 1.0f - 2.0f * frcp(1.0f + fexp(2.0f * x));
}
__device__ __forceinline__ unsigned short f2bf_rne(float f) {
  union { float f; uint32_t u; } v; v.f = f;
  return (unsigned short)((v.u + 0x7FFFu + ((v.u >> 16) & 1u)) >> 16);
}
__device__ __forceinline__ unsigned int cvt_pk_bf16(float lo, float hi) {
  unsigned int r;
  asm("v_cvt_pk_bf16_f32 %0, %1, %2" : "=v"(r) : "v"(lo), "v"(hi));
  return r;
}

// ---- prep: one unit = (bn*8+fid)*12 + chunk; 64 lanes x 8 k-elems ---------
__global__ void prep_w(const float* __restrict__ Wx, const float* __restrict__ Wh,
                       unsigned short* __restrict__ Bt) {
  const int unit = blockIdx.x * 4 + (threadIdx.x >> 6);   // 0..767
  const int lane = threadIdx.x & 63;
  const int kst  = unit % 12;
  const int fidb = unit / 12;            // bn*8 + fid
  const int bn   = fidb >> 3, fid = fidb & 7;
  const int g    = fid >> 1,  wc  = fid & 1;
  const int wcol = g * HDIM + bn * 32 + wc * 16 + (lane & 15);
  const int kb   = kst * 32 + (lane >> 4) * 8;
  unsigned short v[8];
#pragma unroll
  for (int e = 0; e < 8; ++e) {
    const int k = kb + e;                // 0..383; [100,128) zero pad
    float f = 0.0f;
    if (k < INDIM)       f = Wx[(size_t)k * 1024 + wcol];
    else if (k >= 128)   f = Wh[(size_t)(k - 128) * 1024 + wcol];
    v[e] = f2bf_rne(f);
  }
  *reinterpret_cast<u16x8*>(Bt + (size_t)unit * 512 + lane * 8) =
      *reinterpret_cast<u16x8*>(v);
}

// ---- main -----------------------------------------------------------------
__global__ __launch_bounds__(256, 4)
void lstm_main(const float* __restrict__ X, const float* __restrict__ Cin,
               const float* __restrict__ Hin,
               const unsigned short* __restrict__ Bt,
               const float* __restrict__ bxp, const float* __restrict__ bhp,
               float* __restrict__ out)
{
  const int tid  = threadIdx.x;
  const int orig = blockIdx.x;                 // 0..16383 (%8==0 -> bijective)
  const int lg   = ((orig & 7) << 11) | (orig >> 3);
  const int mt   = lg >> 3;                    // M tile 0..2047 (64 rows)
  const int bn   = lg & 7;                     // N tile 0..7 (32 H-cols)

  const int lane = tid & 63;
  const int l15  = lane & 15;
  const int kq   = lane >> 4;                  // k-quarter 0..3
  const int wid  = tid >> 6;                   // 0..3
  const int wr   = wid >> 1;                   // 0..1: 32-row group
  const int wc   = wid & 1;                    // 0..1: 16-hcol half
  const int ch   = bn * 32 + wc * 16 + l15;    // this lane's H column

  // A row pointers for the 2 m-fragments, pre-offset by kq*8 floats
  const float* xrp[2];
  const float* hrp[2];
#pragma unroll
  for (int m = 0; m < 2; ++m) {
    const int row = mt * 64 + wr * 32 + m * 16 + l15;
    xrp[m] = X   + (size_t)row * INDIM + kq * 8;
    hrp[m] = Hin + (size_t)row * HDIM + kq * 8;
  }
  const unsigned short* btb =
      Bt + (size_t)((bn * 8 + wc) * 12) * 512 + lane * 8;  // g via +2*12*512

  f32x4 acc[2][4];                             // [m][gate]
#pragma unroll
  for (int m = 0; m < 2; ++m)
#pragma unroll
    for (int g = 0; g < 4; ++g)
#pragma unroll
      for (int e = 0; e < 4; ++e) acc[m][g][e] = 0.0f;

  float  Abuf[2][16];                          // [c&1][m*8 + j] fp32
  bf16x8 Bbuf[2][4];                           // [c&1][g]

  auto loadA = [&](int c) {
    float (&av)[16] = Abuf[c & 1];
#pragma unroll
    for (int m = 0; m < 2; ++m) {
      float4 lo = make_float4(0.f, 0.f, 0.f, 0.f);
      float4 hi = make_float4(0.f, 0.f, 0.f, 0.f);
      if (c < 3) {
        lo = *reinterpret_cast<const float4*>(xrp[m] + c * 32);
        hi = *reinterpret_cast<const float4*>(xrp[m] + c * 32 + 4);
      } else if (c == 3) {
        if (kq == 0) lo = *reinterpret_cast<const float4*>(xrp[m] + 96);
      } else {
        lo = *reinterpret_cast<const float4*>(hrp[m] + (c - 4) * 32);
        hi = *reinterpret_cast<const float4*>(hrp[m] + (c - 4) * 32 + 4);
      }
      av[m*8+0]=lo.x; av[m*8+1]=lo.y; av[m*8+2]=lo.z; av[m*8+3]=lo.w;
      av[m*8+4]=hi.x; av[m*8+5]=hi.y; av[m*8+6]=hi.z; av[m*8+7]=hi.w;
    }
  };
  auto loadB = [&](int c) {
#pragma unroll
    for (int g = 0; g < 4; ++g)
      Bbuf[c & 1][g] = *reinterpret_cast<const bf16x8*>(
          btb + ((size_t)g * 2 * 12 + c) * 512);
  };

  // prologue: 2 chunks in flight
  loadA(0); loadB(0);
  loadA(1); loadB(1);

  float cvv[16];
  float bias[4];
  const float* cbase = Cin + (size_t)(mt * 64 + wr * 32 + kq * 4) * HDIM + ch;

#pragma unroll
  for (int c = 0; c < 12; ++c) {
    // convert A(c) -> fragments (this is the vmcnt wait point for A(c))
    bf16x8 afr[2];
#pragma unroll
    for (int m = 0; m < 2; ++m) {
      union { u32x4 u; bf16x8 b; } cv;
      cv.u[0] = cvt_pk_bf16(Abuf[c & 1][m*8+0], Abuf[c & 1][m*8+1]);
      cv.u[1] = cvt_pk_bf16(Abuf[c & 1][m*8+2], Abuf[c & 1][m*8+3]);
      cv.u[2] = cvt_pk_bf16(Abuf[c & 1][m*8+4], Abuf[c & 1][m*8+5]);
      cv.u[3] = cvt_pk_bf16(Abuf[c & 1][m*8+6], Abuf[c & 1][m*8+7]);
      afr[m] = cv.b;
    }
    if (c + 2 < 12) loadA(c + 2);              // refill A slot just freed

    __builtin_amdgcn_s_setprio(1);
#pragma unroll
    for (int m = 0; m < 2; ++m)
#pragma unroll
      for (int g = 0; g < 4; ++g)
        acc[m][g] = __builtin_amdgcn_mfma_f32_16x16x32_bf16(
            afr[m], Bbuf[c & 1][g], acc[m][g], 0, 0, 0);
    __builtin_amdgcn_s_setprio(0);

    if (c + 2 < 12) loadB(c + 2);              // refill B slot just freed

    if (c == 9) {                              // epilogue prefetch, 2 chunks out
#pragma unroll
      for (int m = 0; m < 2; ++m)
#pragma unroll
        for (int e = 0; e < 4; ++e)
          cvv[m * 4 + e] = cbase[(size_t)(m * 16 + e) * HDIM];
#pragma unroll
      for (int g = 0; g < 4; ++g)
        bias[g] = bxp[g * HDIM + ch] + bhp[g * HDIM + ch];
    }
  }

  // ---- epilogue: lane-local gate combine (D: col=lane&15, row=kq*4+e) ----
  float* obase  = out + (size_t)(mt * 64 + wr * 32 + kq * 4) * HDIM + ch;
  float* obase2 = obase + (size_t)NROWS * HDIM;
#pragma unroll
  for (int m = 0; m < 2; ++m) {
#pragma unroll
    for (int e = 0; e < 4; ++e) {
      const float pi = acc[m][0][e] + bias[0];
      const float pf = acc[m][1][e] + bias[1];
      const float pg = acc[m][2][e] + bias[2];
      const float po = acc[m][3][e] + bias[3];
      const float ig = sigm(pi), fg = sigm(pf);
      const float gg = tanh_fast(pg), og = sigm(po);
      const float co = fg * cvv[m * 4 + e] + ig * gg;
      const float ho = og * tanh_fast(co);
      obase [(size_t)(m * 16 + e) * HDIM] = co;
      obase2[(size_t)(m * 16 + e) * HDIM] = ho;
    }
  }
}

extern "C" void kernel_launch(void* const* d_in, const int* in_sizes, int n_in,
                              void* d_out, int out_size, void* d_ws, size_t ws_size,
                              hipStream_t stream) {
  const float* x  = (const float*)d_in[0];
  const float* C  = (const float*)d_in[1];
  const float* h  = (const float*)d_in[2];
  const float* Wx = (const float*)d_in[3];
  const float* Wh = (const float*)d_in[4];
  const float* bx = (const float*)d_in[5];
  const float* bh = (const float*)d_in[6];
  float* o = (float*)d_out;
  unsigned short* Bt = (unsigned short*)d_ws;   // 768*512*2 = 786 KiB

  prep_w<<<dim3(192), dim3(256), 0, stream>>>(Wx, Wh, Bt);
  lstm_main<<<dim3(16384), dim3(256), 0, stream>>>(x, C, h, Bt, bx, bh, o);
}

// Round 7
// 354.789 us; speedup vs baseline: 1.5677x; 1.5677x over previous
//
#include <hip/hip_runtime.h>
#include <stdint.h>

// ---------------------------------------------------------------------------
// Fused LSTM cell, round 7: PERSISTENT blocks, barrier-free steady state.
//  prep_w: unchanged — fragment-packed bf16 blob Bt[bn][fid][chunk][lane][8]
//          in d_ws (786 KiB), K zero-padded (x 100->128, h 256).
//  lstm_main: 256 blocks (1/CU) x 512 thr (8 waves, 4 wr x 2 wc).
//    Block owns bn = blk>>5 (32 H-cols) and rows [mpart*4096, +4096).
//    B bn-slice (96 KiB) -> LDS once (fragment-linear blob: ds_read is
//    lane-linear 16B => conflict-free). ONE barrier total.
//    Then 16 M-tiles x 12 chunks as one continuous per-wave stream:
//    3-deep named-register A prefetch (avA/avB/avC, slot = c%3), loads for
//    tile t+1 issued during tile t's chunks 9..11. No __syncthreads, no
//    convoys; 8 independent waves/CU each keep ~24 KB HBM traffic in flight.
// ---------------------------------------------------------------------------

typedef short          bf16x8 __attribute__((ext_vector_type(8)));
typedef unsigned short u16x8  __attribute__((ext_vector_type(8)));
typedef float          f32x4  __attribute__((ext_vector_type(4)));
typedef unsigned int   u32x4  __attribute__((ext_vector_type(4)));

#define HDIM   256
#define INDIM  100
#define NROWS  131072
#define NT     16            // M-tiles per block (256 rows each)

__device__ __forceinline__ float fexp(float x) {
  return __builtin_amdgcn_exp2f(x * 1.44269504088896340736f);
}
__device__ __forceinline__ float frcp(float x) { return __builtin_amdgcn_rcpf(x); }
__device__ __forceinline__ float sigm(float x) { return frcp(1.0f + fexp(-x)); }
__device__ __forceinline__ float tanh_fast(float x) {
  return 1.0f - 2.0f * frcp(1.0f + fexp(2.0f * x));
}
__device__ __forceinline__ unsigned short f2bf_rne(float f) {
  union { float f; uint32_t u; } v; v.f = f;
  return (unsigned short)((v.u + 0x7FFFu + ((v.u >> 16) & 1u)) >> 16);
}
__device__ __forceinline__ unsigned int cvt_pk_bf16(float lo, float hi) {
  unsigned int r;
  asm("v_cvt_pk_bf16_f32 %0, %1, %2" : "=v"(r) : "v"(lo), "v"(hi));
  return r;
}

// ---- prep: one unit = (bn*8+fid)*12 + chunk; 64 lanes x 8 k-elems ---------
__global__ void prep_w(const float* __restrict__ Wx, const float* __restrict__ Wh,
                       unsigned short* __restrict__ Bt) {
  const int unit = blockIdx.x * 4 + (threadIdx.x >> 6);   // 0..767
  const int lane = threadIdx.x & 63;
  const int kst  = unit % 12;
  const int fidb = unit / 12;            // bn*8 + fid
  const int bn   = fidb >> 3, fid = fidb & 7;
  const int g    = fid >> 1,  wc  = fid & 1;
  const int wcol = g * HDIM + bn * 32 + wc * 16 + (lane & 15);
  const int kb   = kst * 32 + (lane >> 4) * 8;
  unsigned short v[8];
#pragma unroll
  for (int e = 0; e < 8; ++e) {
    const int k = kb + e;                // 0..383; [100,128) zero pad
    float f = 0.0f;
    if (k < INDIM)       f = Wx[(size_t)k * 1024 + wcol];
    else if (k >= 128)   f = Wh[(size_t)(k - 128) * 1024 + wcol];
    v[e] = f2bf_rne(f);
  }
  *reinterpret_cast<u16x8*>(Bt + (size_t)unit * 512 + lane * 8) =
      *reinterpret_cast<u16x8*>(v);
}

// ---- main -----------------------------------------------------------------
__global__ __launch_bounds__(512, 2)
void lstm_main(const float* __restrict__ X, const float* __restrict__ Cin,
               const float* __restrict__ Hin,
               const unsigned short* __restrict__ Bt,
               const float* __restrict__ bxp, const float* __restrict__ bhp,
               float* __restrict__ out)
{
  __shared__ uint4 BsV[6144];                  // 96 KiB B blob (bn slice)
  unsigned short* Bs = (unsigned short*)BsV;

  const int tid   = threadIdx.x;
  const int blk   = blockIdx.x;                // 0..255
  const int bn    = blk >> 5;                  // 0..7  (siblings share blk%8)
  const int mpart = blk & 31;                  // 0..31
  const int lane  = tid & 63;
  const int l15   = lane & 15;
  const int kq    = lane >> 4;
  const int wid   = tid >> 6;                  // 0..7
  const int wr    = wid >> 1;                  // 0..3: 64-row group
  const int wc    = wid & 1;                   // 0..1: 16-hcol half
  const int ch    = bn * 32 + wc * 16 + l15;

  // A row pointers for 4 m-frags, pre-offset kq*8; advanced +256 rows/tile
  const float* xp[4];
  const float* hp[4];
#pragma unroll
  for (int m = 0; m < 4; ++m) {
    const size_t row = (size_t)mpart * 4096 + wr * 64 + m * 16 + l15;
    xp[m] = X   + row * INDIM + kq * 8;
    hp[m] = Hin + row * HDIM + kq * 8;
  }

  float avA[32], avB[32], avC[32];             // 3-deep prefetch slots

  // load effective chunk ec (0..11) of the CURRENT pointer position into av
  auto loadA = [&](int ec, float (&av)[32]) {
#pragma unroll
    for (int m = 0; m < 4; ++m) {
      float4 lo = make_float4(0.f, 0.f, 0.f, 0.f);
      float4 hi = make_float4(0.f, 0.f, 0.f, 0.f);
      if (ec < 3) {
        lo = *reinterpret_cast<const float4*>(xp[m] + ec * 32);
        hi = *reinterpret_cast<const float4*>(xp[m] + ec * 32 + 4);
      } else if (ec == 3) {
        if (kq == 0) lo = *reinterpret_cast<const float4*>(xp[m] + 96);
      } else {
        lo = *reinterpret_cast<const float4*>(hp[m] + (ec - 4) * 32);
        hi = *reinterpret_cast<const float4*>(hp[m] + (ec - 4) * 32 + 4);
      }
      av[m*8+0]=lo.x; av[m*8+1]=lo.y; av[m*8+2]=lo.z; av[m*8+3]=lo.w;
      av[m*8+4]=hi.x; av[m*8+5]=hi.y; av[m*8+6]=hi.z; av[m*8+7]=hi.w;
    }
  };

  // prologue: 3 chunks of tile 0 in flight
  loadA(0, avA);
  loadA(1, avB);
  loadA(2, avC);

  // B slice -> LDS (fragment-linear blob, both sides linear)
  const uint4* bsrc = reinterpret_cast<const uint4*>(Bt + (size_t)bn * 49152);
#pragma unroll
  for (int i = 0; i < 12; ++i) BsV[i * 512 + tid] = bsrc[i * 512 + tid];
  __syncthreads();                             // the ONLY barrier

  float bias[4];
#pragma unroll
  for (int g = 0; g < 4; ++g) bias[g] = bxp[g * HDIM + ch] + bhp[g * HDIM + ch];

  f32x4 acc[4][4];
#pragma unroll
  for (int m = 0; m < 4; ++m)
#pragma unroll
    for (int g = 0; g < 4; ++g)
#pragma unroll
      for (int e = 0; e < 4; ++e) acc[m][g][e] = 0.0f;

  const float* cbase =
      Cin + ((size_t)mpart * 4096 + wr * 64 + kq * 4) * HDIM + ch;
  float* obase  = out + ((size_t)mpart * 4096 + wr * 64 + kq * 4) * HDIM + ch;
  float* obase2 = obase + (size_t)NROWS * HDIM;

  float cvv[16];

  // one step: consume av (chunk c of tile t), refill SAME av with chunk c+3
  auto do_step = [&](int c, float (&av)[32], int t) {
    bf16x8 afr[4];
#pragma unroll
    for (int m = 0; m < 4; ++m) {
      union { u32x4 u; bf16x8 b; } cv;
      cv.u[0] = cvt_pk_bf16(av[m*8+0], av[m*8+1]);
      cv.u[1] = cvt_pk_bf16(av[m*8+2], av[m*8+3]);
      cv.u[2] = cvt_pk_bf16(av[m*8+4], av[m*8+5]);
      cv.u[3] = cvt_pk_bf16(av[m*8+6], av[m*8+7]);
      afr[m] = cv.b;
    }
    // refill: chunks 0..8 -> ec=c+3 (tile t); 9..11 -> ec=c-9 (tile t+1,
    // pointers already advanced). Skip on the last tile's next-tile loads.
    if (c < 9) {
      loadA(c + 3, av);
    } else if (t < NT - 1) {
      loadA(c - 9, av);
    }

    bf16x8 bfr[4];
#pragma unroll
    for (int g = 0; g < 4; ++g)
      bfr[g] = *reinterpret_cast<const bf16x8*>(
          &Bs[(size_t)(((g * 2 + wc) * 12 + c) * 512) + lane * 8]);

    __builtin_amdgcn_s_setprio(1);
#pragma unroll
    for (int m = 0; m < 4; ++m)
#pragma unroll
      for (int g = 0; g < 4; ++g)
        acc[m][g] = __builtin_amdgcn_mfma_f32_16x16x32_bf16(
            afr[m], bfr[g], acc[m][g], 0, 0, 0);
    __builtin_amdgcn_s_setprio(0);
  };

#pragma unroll 1
  for (int t = 0; t < NT; ++t) {
    do_step(0, avA, t);  do_step(1, avB, t);  do_step(2, avC, t);
    do_step(3, avA, t);  do_step(4, avB, t);  do_step(5, avC, t);
    do_step(6, avA, t);  do_step(7, avB, t);
    do_step(8, avC, t);                        // issues ec=11 (last of tile t)
    // advance pointers to tile t+1 before next-tile prefetches
#pragma unroll
    for (int m = 0; m < 4; ++m) { xp[m] += 256 * INDIM; hp[m] += 256 * HDIM; }
    do_step(9, avA, t);
    do_step(10, avB, t);
    // C prefetch for this tile's epilogue
    {
      const float* cp = cbase + (size_t)t * 256 * HDIM;
#pragma unroll
      for (int m = 0; m < 4; ++m)
#pragma unroll
        for (int e = 0; e < 4; ++e)
          cvv[m * 4 + e] = cp[(size_t)(m * 16 + e) * HDIM];
    }
    do_step(11, avC, t);

    // epilogue: lane-local gate combine (D: col=lane&15, row=kq*4+e)
    float* op  = obase  + (size_t)t * 256 * HDIM;
    float* op2 = obase2 + (size_t)t * 256 * HDIM;
#pragma unroll
    for (int m = 0; m < 4; ++m) {
#pragma unroll
      for (int e = 0; e < 4; ++e) {
        const float pi = acc[m][0][e] + bias[0];
        const float pf = acc[m][1][e] + bias[1];
        const float pg = acc[m][2][e] + bias[2];
        const float po = acc[m][3][e] + bias[3];
        const float ig = sigm(pi), fg = sigm(pf);
        const float gg = tanh_fast(pg), og = sigm(po);
        const float co = fg * cvv[m * 4 + e] + ig * gg;
        const float ho = og * tanh_fast(co);
        op [(size_t)(m * 16 + e) * HDIM] = co;
        op2[(size_t)(m * 16 + e) * HDIM] = ho;
      }
    }
#pragma unroll
    for (int m = 0; m < 4; ++m)
#pragma unroll
      for (int g = 0; g < 4; ++g)
#pragma unroll
        for (int e = 0; e < 4; ++e) acc[m][g][e] = 0.0f;
  }
}

extern "C" void kernel_launch(void* const* d_in, const int* in_sizes, int n_in,
                              void* d_out, int out_size, void* d_ws, size_t ws_size,
                              hipStream_t stream) {
  const float* x  = (const float*)d_in[0];
  const float* C  = (const float*)d_in[1];
  const float* h  = (const float*)d_in[2];
  const float* Wx = (const float*)d_in[3];
  const float* Wh = (const float*)d_in[4];
  const float* bx = (const float*)d_in[5];
  const float* bh = (const float*)d_in[6];
  float* o = (float*)d_out;
  unsigned short* Bt = (unsigned short*)d_ws;   // 768*512*2 = 786 KiB

  prep_w<<<dim3(192), dim3(256), 0, stream>>>(Wx, Wh, Bt);
  lstm_main<<<dim3(256), dim3(512), 0, stream>>>(x, C, h, Bt, bx, bh, o);
}

// Round 8
// 303.015 us; speedup vs baseline: 1.8356x; 1.1709x over previous
//
#include <hip/hip_runtime.h>
#include <stdint.h>

// ---------------------------------------------------------------------------
// Fused LSTM cell, round 8: global_load_lds streaming + counted vmcnt (T3/T4).
//  prep_w: W -> fragment-packed bf16 blob Bt[(bn*8+fid)*12+stage][lane][8e]
//          (1 KiB units in d_ws). K zero-padded; k==127 slot holds bx+bh
//          (bias folded into the GEMM: A supplies 1.0 at k=127).
//  lstm_main: 256 thr (4 waves: 2 wr x 2 wc), block = 64 rows x 128 gatecols.
//    12 stages of BK=32. A (fp32, XOR-chunk-swizzled via pre-swizzled global
//    src) and B (bf16 blob, linear) stream via global_load_lds into a 3-deep
//    LDS multibuffer (48 KiB). Exactly 4 gl_lds per wave per stage ->
//    vmcnt(4) + s_barrier per stage keeps 2 stages (8 loads) in flight
//    across barriers. acc[2][4]=32 AGPR -> 12 waves/CU. NT stores.
// ---------------------------------------------------------------------------

typedef short bf16x8 __attribute__((ext_vector_type(8)));
typedef float f32x4  __attribute__((ext_vector_type(4)));

#define HDIM   256
#define INDIM  100
#define NROWS  131072
#define ABUF(b) ((b) * 8192)
#define BBUF(b) (24576 + (b) * 8192)

__device__ __forceinline__ float fexp(float x) {
  return __builtin_amdgcn_exp2f(x * 1.44269504088896340736f);
}
__device__ __forceinline__ float frcp(float x) { return __builtin_amdgcn_rcpf(x); }
__device__ __forceinline__ float sigm(float x) { return frcp(1.0f + fexp(-x)); }
__device__ __forceinline__ float tanh_fast(float x) {
  return 1.0f - 2.0f * frcp(1.0f + fexp(2.0f * x));
}
__device__ __forceinline__ unsigned short f2bf_rne(float f) {
  union { float f; uint32_t u; } v; v.f = f;
  return (unsigned short)((v.u + 0x7FFFu + ((v.u >> 16) & 1u)) >> 16);
}
__device__ __forceinline__ unsigned int cvt_pk_bf16(float lo, float hi) {
  unsigned int r;
  asm("v_cvt_pk_bf16_f32 %0, %1, %2" : "=v"(r) : "v"(lo), "v"(hi));
  return r;
}
__device__ __forceinline__ void gl16(const void* g, void* l) {
  __builtin_amdgcn_global_load_lds(
      (const __attribute__((address_space(1))) unsigned int*)g,
      (__attribute__((address_space(3))) unsigned int*)l, 16, 0, 0);
}
#define VMW(N) asm volatile("s_waitcnt vmcnt(" #N ")" ::: "memory")

// ---- prep: unit = (bn*8+fid)*12 + stage; 64 lanes x 8 k-elems; bias@k127 --
__global__ void prep_w(const float* __restrict__ Wx, const float* __restrict__ Wh,
                       const float* __restrict__ bxp, const float* __restrict__ bhp,
                       unsigned short* __restrict__ Bt) {
  const int unit = blockIdx.x * 4 + (threadIdx.x >> 6);   // 0..767
  const int lane = threadIdx.x & 63;
  const int kst  = unit % 12;
  const int fidb = unit / 12;
  const int bn   = fidb >> 3, fid = fidb & 7;
  const int g    = fid >> 1,  wc  = fid & 1;
  const int wcol = g * HDIM + bn * 32 + wc * 16 + (lane & 15);
  const int kb   = kst * 32 + (lane >> 4) * 8;
  unsigned short v[8];
#pragma unroll
  for (int e = 0; e < 8; ++e) {
    const int k = kb + e;                // 0..383
    float f = 0.0f;
    if (k < INDIM)       f = Wx[(size_t)k * 1024 + wcol];
    else if (k == 127)   f = bxp[wcol] + bhp[wcol];       // bias slot
    else if (k >= 128)   f = Wh[(size_t)(k - 128) * 1024 + wcol];
    v[e] = f2bf_rne(f);
  }
  *reinterpret_cast<bf16x8*>(Bt + (size_t)unit * 512 + lane * 8) =
      *reinterpret_cast<bf16x8*>(v);
}

// ---- main -----------------------------------------------------------------
__global__ __launch_bounds__(256, 3)
void lstm_main(const float* __restrict__ X, const float* __restrict__ Cin,
               const float* __restrict__ Hin,
               const unsigned short* __restrict__ Bt,
               float* __restrict__ out)
{
  __shared__ unsigned char smem[49152];        // 3x(8K A + 8K B)

  const int tid  = threadIdx.x;
  const int orig = blockIdx.x;                 // 0..16383 (%8==0 -> bijective)
  const int lg   = ((orig & 7) << 11) | (orig >> 3);
  const int mt   = lg >> 3;                    // M tile 0..2047 (64 rows)
  const int bn   = lg & 7;                     // N tile 0..7 (32 H-cols)

  const int lane = tid & 63;
  const int l15  = lane & 15;
  const int kq   = lane >> 4;
  const int wid  = tid >> 6;                   // 0..3
  const int wr   = wid >> 1;                   // 0..1: 32-row group
  const int wc   = wid & 1;                    // 0..1: 16-hcol half
  const int ch   = bn * 32 + wc * 16 + l15;

  // staging sources (2 gl_lds ops each for A and B per stage)
  const char* xsrc[2]; const char* x3src[2]; const char* hsrc[2];
  const char* btsrc[2];
#pragma unroll
  for (int j = 0; j < 2; ++j) {
    const int ci = (wid * 2 + j) * 64 + lane;  // 0..511
    const int r  = ci >> 3;                    // tile row 0..63
    const int cl = (ci & 7) ^ (r & 7);         // inverse-swizzled chunk
    xsrc[j]  = (const char*)(X   + (size_t)(mt * 64 + r) * INDIM) + cl * 16;
    hsrc[j]  = (const char*)(Hin + (size_t)(mt * 64 + r) * HDIM) + cl * 16;
    // stage 3 (k 96..127): only chunk 0 (k96..99) is real; clamp rest in-bounds
    x3src[j] = (cl == 0) ? xsrc[j] + 384 : (const char*)X;
    btsrc[j] = (const char*)Bt +
               (size_t)((bn * 8 + wid * 2 + j) * 12) * 1024 + lane * 16;
  }
  const int aoff0 = (wid * 2 + 0) * 1024;      // wave-uniform LDS sub-offsets
  const int aoff1 = (wid * 2 + 1) * 1024;

  f32x4 acc[2][4];
#pragma unroll
  for (int m = 0; m < 2; ++m)
#pragma unroll
    for (int g = 0; g < 4; ++g)
#pragma unroll
      for (int e = 0; e < 4; ++e) acc[m][g][e] = 0.0f;

  float cvv[2][4];

  // issue the 4 gl_lds for stage T into buffer T%3
  auto STAGE = [&](int T) {
    char* Ad = (char*)smem + ABUF(T % 3);
    char* Bd = (char*)smem + BBUF(T % 3);
    if (T < 3) {
      gl16(xsrc[0] + T * 128, Ad + aoff0);
      gl16(xsrc[1] + T * 128, Ad + aoff1);
    } else if (T == 3) {
      gl16(x3src[0], Ad + aoff0);
      gl16(x3src[1], Ad + aoff1);
    } else {
      gl16(hsrc[0] + (T - 4) * 128, Ad + aoff0);
      gl16(hsrc[1] + (T - 4) * 128, Ad + aoff1);
    }
    gl16(btsrc[0] + T * 1024, Bd + aoff0);
    gl16(btsrc[1] + T * 1024, Bd + aoff1);
  };

  auto COMPUTE = [&](int S) {
    const float* Abf = (const float*)((const char*)smem + ABUF(S % 3));
    const char*  Bbf = (const char*)smem + BBUF(S % 3);
    const int sw = l15 & 7;
    bf16x8 afr[2];
#pragma unroll
    for (int m = 0; m < 2; ++m) {
      const int R = wr * 32 + m * 16 + l15;
      float4 lo = *reinterpret_cast<const float4*>(
          Abf + R * 32 + (((2 * kq) ^ sw) * 4));
      float4 hi = *reinterpret_cast<const float4*>(
          Abf + R * 32 + (((2 * kq + 1) ^ sw) * 4));
      if (S == 3) {                            // ragged x tail + bias lane
        if (kq != 0) { lo.x = 0.f; lo.y = 0.f; lo.z = 0.f; lo.w = 0.f; }
        hi.x = 0.f; hi.y = 0.f; hi.z = 0.f;
        hi.w = (kq == 3) ? 1.0f : 0.0f;        // k=127 -> bias row
      }
      union { unsigned int u[4]; bf16x8 b; } cv;
      cv.u[0] = cvt_pk_bf16(lo.x, lo.y);
      cv.u[1] = cvt_pk_bf16(lo.z, lo.w);
      cv.u[2] = cvt_pk_bf16(hi.x, hi.y);
      cv.u[3] = cvt_pk_bf16(hi.z, hi.w);
      afr[m] = cv.b;
    }
    __builtin_amdgcn_s_setprio(1);
#pragma unroll
    for (int m = 0; m < 2; ++m)
#pragma unroll
      for (int g = 0; g < 4; ++g) {
        const bf16x8 bfr = *reinterpret_cast<const bf16x8*>(
            Bbf + (g * 2 + wc) * 1024 + lane * 16);
        acc[m][g] = __builtin_amdgcn_mfma_f32_16x16x32_bf16(
            afr[m], bfr, acc[m][g], 0, 0, 0);
      }
    __builtin_amdgcn_s_setprio(0);
  };

  // prologue: stages 0,1 in flight (8 gl_lds)
  STAGE(0);
  STAGE(1);

#define STEP(S, KN)                                              \
  do {                                                           \
    VMW(KN);                                                     \
    __builtin_amdgcn_s_barrier();                                \
    if ((S) + 2 < 12) STAGE((S) + 2);                            \
    if ((S) == 10) {  /* C prefetch: 8 loads, counted in K(11) */\
      const float* cb =                                          \
          Cin + ((size_t)mt * 64 + wr * 32 + kq * 4) * HDIM + ch;\
      _Pragma("unroll")                                          \
      for (int m = 0; m < 2; ++m)                                \
        _Pragma("unroll")                                        \
        for (int e = 0; e < 4; ++e)                              \
          cvv[m][e] = cb[(size_t)(m * 16 + e) * HDIM];           \
    }                                                            \
    COMPUTE(S);                                                  \
  } while (0)

  STEP(0, 4);  STEP(1, 4);  STEP(2, 4);  STEP(3, 4);
  STEP(4, 4);  STEP(5, 4);  STEP(6, 4);  STEP(7, 4);
  STEP(8, 4);  STEP(9, 4);  STEP(10, 4); STEP(11, 8);
#undef STEP

  // ---- epilogue: bias already in acc via k=127; lane-local combine -------
  const size_t rbase = (size_t)mt * 64 + wr * 32 + kq * 4;
  float* op  = out + rbase * HDIM + ch;
  float* op2 = op + (size_t)NROWS * HDIM;
#pragma unroll
  for (int m = 0; m < 2; ++m) {
#pragma unroll
    for (int e = 0; e < 4; ++e) {
      const float pi = acc[m][0][e];
      const float pf = acc[m][1][e];
      const float pg = acc[m][2][e];
      const float po = acc[m][3][e];
      const float ig = sigm(pi), fg = sigm(pf);
      const float gg = tanh_fast(pg), og = sigm(po);
      const float co = fg * cvv[m][e] + ig * gg;
      const float ho = og * tanh_fast(co);
      __builtin_nontemporal_store(co, &op [(size_t)(m * 16 + e) * HDIM]);
      __builtin_nontemporal_store(ho, &op2[(size_t)(m * 16 + e) * HDIM]);
    }
  }
}

extern "C" void kernel_launch(void* const* d_in, const int* in_sizes, int n_in,
                              void* d_out, int out_size, void* d_ws, size_t ws_size,
                              hipStream_t stream) {
  const float* x  = (const float*)d_in[0];
  const float* C  = (const float*)d_in[1];
  const float* h  = (const float*)d_in[2];
  const float* Wx = (const float*)d_in[3];
  const float* Wh = (const float*)d_in[4];
  const float* bx = (const float*)d_in[5];
  const float* bh = (const float*)d_in[6];
  float* o = (float*)d_out;
  unsigned short* Bt = (unsigned short*)d_ws;   // 768 KiB blob

  prep_w<<<dim3(192), dim3(256), 0, stream>>>(Wx, Wh, bx, bh, Bt);
  lstm_main<<<dim3(16384), dim3(256), 0, stream>>>(x, C, h, Bt, o);
}

// Round 9
// 248.842 us; speedup vs baseline: 2.2352x; 1.2177x over previous
//
#include <hip/hip_runtime.h>
#include <stdint.h>

// ---------------------------------------------------------------------------
// Fused LSTM cell, round 9: prep-converted bf16 operands + pure m97-shape loop.
//  prep_all (one kernel, 3 jobs by blockIdx):
//    xb[131072][128] bf16: x zero-padded, k==127 slot = 1.0 (bias row driver)
//    hb[131072][256] bf16
//    Bt fragment blob (as r8): unit=(bn*8+fid)*12+kst, k==127 = bx+bh (bias)
//  lstm_main: 256 thr (4 waves, 2 wr x 2 wc), tile 128 rows x 128 gate-cols,
//    12 stages of BK=32. Per wave per stage: 4 gl_lds (2 A + 2 B, homogeneous
//    vmcnt FIFO) + 8 ds_read_b128 + 16 MFMA. No cvt, no guards in the loop.
//    A-LDS XOR swizzle chunk^((row>>1)&3) (2-way = free), write side via
//    pre-swizzled GLOBAL source (linear gl_lds dest). B lane-linear.
//    LDS 32 KiB dbuf -> launch_bounds(256,4) -> 16 waves/CU.
// ---------------------------------------------------------------------------

typedef short bf16x8 __attribute__((ext_vector_type(8)));
typedef float f32x4  __attribute__((ext_vector_type(4)));

#define HDIM   256
#define INDIM  100
#define NROWS  131072
// d_ws layout (ushort offsets): Bt @0 (768 KiB), xb @1 MiB, hb @34 MiB
#define BT_OFF 0
#define XB_OFF (1048576 / 2)
#define HB_OFF (35651584 / 2)

__device__ __forceinline__ float fexp(float x) {
  return __builtin_amdgcn_exp2f(x * 1.44269504088896340736f);
}
__device__ __forceinline__ float frcp(float x) { return __builtin_amdgcn_rcpf(x); }
__device__ __forceinline__ float sigm(float x) { return frcp(1.0f + fexp(-x)); }
__device__ __forceinline__ float tanh_fast(float x) {
  return 1.0f - 2.0f * frcp(1.0f + fexp(2.0f * x));
}
__device__ __forceinline__ unsigned short f2bf_rne(float f) {
  union { float f; uint32_t u; } v; v.f = f;
  return (unsigned short)((v.u + 0x7FFFu + ((v.u >> 16) & 1u)) >> 16);
}
__device__ __forceinline__ void gl16(const void* g, void* l) {
  __builtin_amdgcn_global_load_lds(
      (const __attribute__((address_space(1))) unsigned int*)g,
      (__attribute__((address_space(3))) unsigned int*)l, 16, 0, 0);
}
#define VMW(N) asm volatile("s_waitcnt vmcnt(" #N ")" ::: "memory")

// ---- prep: 3 jobs ---------------------------------------------------------
__global__ void prep_all(const float* __restrict__ X, const float* __restrict__ Hin,
                         const float* __restrict__ Wx, const float* __restrict__ Wh,
                         const float* __restrict__ bxp, const float* __restrict__ bhp,
                         unsigned short* __restrict__ ws) {
  const int b = blockIdx.x, tid = threadIdx.x;
  if (b < 8192) {                        // ---- x -> xb[131072][128] ----
    const int t   = b * 256 + tid;       // 0..2M-1
    const int row = t >> 4, k0 = (t & 15) * 8;
    const float* xp = X + (size_t)row * INDIM;
    float4 lo = make_float4(0.f, 0.f, 0.f, 0.f);
    float4 hi = make_float4(0.f, 0.f, 0.f, 0.f);
    if (k0 + 4 <= INDIM) lo = *reinterpret_cast<const float4*>(xp + k0);
    if (k0 + 8 <= INDIM) hi = *reinterpret_cast<const float4*>(xp + k0 + 4);
    float va[8] = {lo.x, lo.y, lo.z, lo.w, hi.x, hi.y, hi.z, hi.w};
    unsigned short o[8];
#pragma unroll
    for (int e = 0; e < 8; ++e) {
      const int k = k0 + e;
      const float f = (k < INDIM) ? va[e] : (k == 127 ? 1.0f : 0.0f);
      o[e] = f2bf_rne(f);
    }
    *reinterpret_cast<bf16x8*>(ws + XB_OFF + (size_t)row * 128 + k0) =
        *reinterpret_cast<bf16x8*>(o);
  } else if (b < 24576) {                // ---- h -> hb[131072][256] ----
    const int t   = (b - 8192) * 256 + tid;   // 0..4M-1
    const int row = t >> 5, k0 = (t & 31) * 8;
    const float* hp = Hin + (size_t)row * HDIM + k0;
    const float4 lo = *reinterpret_cast<const float4*>(hp);
    const float4 hi = *reinterpret_cast<const float4*>(hp + 4);
    unsigned short o[8] = {f2bf_rne(lo.x), f2bf_rne(lo.y), f2bf_rne(lo.z),
                           f2bf_rne(lo.w), f2bf_rne(hi.x), f2bf_rne(hi.y),
                           f2bf_rne(hi.z), f2bf_rne(hi.w)};
    *reinterpret_cast<bf16x8*>(ws + HB_OFF + (size_t)row * 256 + k0) =
        *reinterpret_cast<bf16x8*>(o);
  } else {                               // ---- W -> Bt blob (bias @ k127) --
    const int unit = (b - 24576) * 4 + (tid >> 6);   // 0..767
    const int lane = tid & 63;
    const int kst  = unit % 12;
    const int fidb = unit / 12;
    const int bn   = fidb >> 3, fid = fidb & 7;
    const int g    = fid >> 1,  wc  = fid & 1;
    const int wcol = g * HDIM + bn * 32 + wc * 16 + (lane & 15);
    const int kb   = kst * 32 + (lane >> 4) * 8;
    unsigned short v[8];
#pragma unroll
    for (int e = 0; e < 8; ++e) {
      const int k = kb + e;              // 0..383
      float f = 0.0f;
      if (k < INDIM)     f = Wx[(size_t)k * 1024 + wcol];
      else if (k == 127) f = bxp[wcol] + bhp[wcol];
      else if (k >= 128) f = Wh[(size_t)(k - 128) * 1024 + wcol];
      v[e] = f2bf_rne(f);
    }
    *reinterpret_cast<bf16x8*>(ws + BT_OFF + (size_t)unit * 512 + lane * 8) =
        *reinterpret_cast<bf16x8*>(v);
  }
}

// ---- main -----------------------------------------------------------------
__global__ __launch_bounds__(256, 4)
void lstm_main(const unsigned short* __restrict__ ws,
               const float* __restrict__ Cin, float* __restrict__ out)
{
  __shared__ unsigned char smem[32768];  // A dbuf 2x8K @0, B dbuf 2x8K @16K

  const int tid  = threadIdx.x;
  const int orig = blockIdx.x;           // 0..8191 (%8==0 -> bijective)
  const int lg   = ((orig & 7) << 10) | (orig >> 3);
  const int mt   = lg >> 3;              // M tile 0..1023 (128 rows)
  const int bn   = lg & 7;               // N tile 0..7 (32 H-cols)

  const int lane = tid & 63;
  const int l15  = lane & 15;
  const int kq   = lane >> 4;
  const int wid  = tid >> 6;             // 0..3
  const int wr   = wid >> 1;             // 0..1: 64-row group
  const int wc   = wid & 1;              // 0..1: 16-hcol half
  const int ch   = bn * 32 + wc * 16 + l15;
  const int sx   = (l15 >> 1) & 3;       // read-side XOR (== (row>>1)&3)

  const unsigned short* xb = ws + XB_OFF;
  const unsigned short* hb = ws + HB_OFF;
  const unsigned short* Bt = ws + BT_OFF;

  // staging sources: per wave 2 A-units + 2 B-units per stage
  const unsigned short* xsrc[2];
  const unsigned short* hsrc[2];
  const unsigned short* bsrc[2];
#pragma unroll
  for (int j = 0; j < 2; ++j) {
    const int ci  = (wid * 2 + j) * 64 + lane;     // 0..511
    const int r   = ci >> 2;                       // tile row 0..127
    const int sc  = (ci & 3) ^ ((r >> 1) & 3);     // pre-swizzled chunk
    xsrc[j] = xb + (size_t)(mt * 128 + r) * 128 + sc * 8;
    hsrc[j] = hb + (size_t)(mt * 128 + r) * 256 + sc * 8;
    bsrc[j] = Bt + (size_t)((bn * 8 + wid * 2 + j) * 12) * 512 + lane * 8;
  }
  const int au0 = (wid * 2 + 0) * 1024;  // wave-uniform LDS sub-offsets (B)
  const int au1 = (wid * 2 + 1) * 1024;

  f32x4 acc[4][4];
#pragma unroll
  for (int m = 0; m < 4; ++m)
#pragma unroll
    for (int g = 0; g < 4; ++g)
#pragma unroll
      for (int e = 0; e < 4; ++e) acc[m][g][e] = 0.0f;

  float cvv[4][4];

  auto STAGE = [&](int T) {
    char* Ad = (char*)smem + (T & 1) * 8192;
    char* Bd = (char*)smem + 16384 + (T & 1) * 8192;
    if (T < 4) {
      gl16(xsrc[0] + T * 32, Ad + au0);
      gl16(xsrc[1] + T * 32, Ad + au1);
    } else {
      gl16(hsrc[0] + (T - 4) * 32, Ad + au0);
      gl16(hsrc[1] + (T - 4) * 32, Ad + au1);
    }
    gl16(bsrc[0] + T * 512, Bd + au0);
    gl16(bsrc[1] + T * 512, Bd + au1);
  };

  auto COMPUTE = [&](int S) {
    const unsigned short* Ab = (const unsigned short*)(smem + (S & 1) * 8192);
    const unsigned short* Bb =
        (const unsigned short*)(smem + 16384 + (S & 1) * 8192);
    bf16x8 afr[4], bfr[4];
#pragma unroll
    for (int m = 0; m < 4; ++m)
      afr[m] = *reinterpret_cast<const bf16x8*>(
          Ab + (wr * 64 + m * 16 + l15) * 32 + ((kq ^ sx) * 8));
#pragma unroll
    for (int g = 0; g < 4; ++g)
      bfr[g] = *reinterpret_cast<const bf16x8*>(
          Bb + (g * 2 + wc) * 512 + lane * 8);
    __builtin_amdgcn_s_setprio(1);
#pragma unroll
    for (int m = 0; m < 4; ++m)
#pragma unroll
      for (int g = 0; g < 4; ++g)
        acc[m][g] = __builtin_amdgcn_mfma_f32_16x16x32_bf16(
            afr[m], bfr[g], acc[m][g], 0, 0, 0);
    __builtin_amdgcn_s_setprio(0);
  };

  STAGE(0);                              // prologue

#define STEP(S, KN)                                               \
  do {                                                            \
    VMW(KN);                                                      \
    __builtin_amdgcn_s_barrier();                                 \
    asm volatile("" ::: "memory");                                \
    if ((S) + 1 < 12) STAGE((S) + 1);                             \
    if ((S) == 9) {                                               \
      const float* cb =                                           \
          Cin + ((size_t)mt * 128 + wr * 64 + kq * 4) * HDIM + ch;\
      _Pragma("unroll")                                           \
      for (int m = 0; m < 4; ++m)                                 \
        _Pragma("unroll")                                         \
        for (int e = 0; e < 4; ++e)                               \
          cvv[m][e] = cb[(size_t)(m * 16 + e) * HDIM];            \
    }                                                             \
    COMPUTE(S);                                                   \
  } while (0)

  STEP(0, 0);  STEP(1, 0);  STEP(2, 0);  STEP(3, 0);
  STEP(4, 0);  STEP(5, 0);  STEP(6, 0);  STEP(7, 0);
  STEP(8, 0);  STEP(9, 0);  STEP(10, 16); STEP(11, 0);
#undef STEP

  // ---- epilogue: bias folded in acc; lane-local gate combine -------------
  float* op  = out + ((size_t)mt * 128 + wr * 64 + kq * 4) * HDIM + ch;
  float* op2 = op + (size_t)NROWS * HDIM;
#pragma unroll
  for (int m = 0; m < 4; ++m) {
#pragma unroll
    for (int e = 0; e < 4; ++e) {
      const float pi = acc[m][0][e];
      const float pf = acc[m][1][e];
      const float pg = acc[m][2][e];
      const float po = acc[m][3][e];
      const float ig = sigm(pi), fg = sigm(pf);
      const float gg = tanh_fast(pg), og = sigm(po);
      const float co = fg * cvv[m][e] + ig * gg;
      const float ho = og * tanh_fast(co);
      op [(size_t)(m * 16 + e) * HDIM] = co;
      op2[(size_t)(m * 16 + e) * HDIM] = ho;
    }
  }
}

extern "C" void kernel_launch(void* const* d_in, const int* in_sizes, int n_in,
                              void* d_out, int out_size, void* d_ws, size_t ws_size,
                              hipStream_t stream) {
  const float* x  = (const float*)d_in[0];
  const float* C  = (const float*)d_in[1];
  const float* h  = (const float*)d_in[2];
  const float* Wx = (const float*)d_in[3];
  const float* Wh = (const float*)d_in[4];
  const float* bx = (const float*)d_in[5];
  const float* bh = (const float*)d_in[6];
  float* o = (float*)d_out;
  unsigned short* ws = (unsigned short*)d_ws;   // ~98 MiB used

  prep_all<<<dim3(24768), dim3(256), 0, stream>>>(x, h, Wx, Wh, bx, bh, ws);
  lstm_main<<<dim3(8192), dim3(256), 0, stream>>>(ws, C, o);
}

// Round 10
// 213.673 us; speedup vs baseline: 2.6031x; 1.1646x over previous
//
#include <hip/hip_runtime.h>
#include <stdint.h>

// ---------------------------------------------------------------------------
// Fused LSTM cell, round 10 = round 9 + 3-deep pipeline + counted vmcnt.
//  prep_all: xb[131072][128] bf16 (pad, k127=1.0), hb[131072][256] bf16,
//            Bt fragment blob (bias @ k127). Unchanged from r9.
//  lstm_main: 256 thr (4 waves, 2x2), tile 128 rows x 128 gate-cols, 12
//    stages BK=32. Per wave per stage: 4 gl_lds (2 A + 2 B, homogeneous
//    vmcnt FIFO) + 8 ds_read_b128 + 16 MFMA. LDS = 3-deep multibuffer
//    (48 KiB). Schedule: VMW(4); barrier; STAGE(S+2); COMPUTE(S) -> two
//    stages always in flight, no vmcnt(0) drain in the loop. C-prefetch
//    FIFO-accounted: VMW(12) @S=10, VMW(8) @S=11.
// ---------------------------------------------------------------------------

typedef short bf16x8 __attribute__((ext_vector_type(8)));
typedef float f32x4  __attribute__((ext_vector_type(4)));

#define HDIM   256
#define INDIM  100
#define NROWS  131072
// d_ws layout (ushort offsets): Bt @0 (768 KiB), xb @1 MiB, hb @34 MiB
#define BT_OFF 0
#define XB_OFF (1048576 / 2)
#define HB_OFF (35651584 / 2)
#define ABUF(b) ((b) * 8192)
#define BBUF(b) (24576 + (b) * 8192)

__device__ __forceinline__ float fexp(float x) {
  return __builtin_amdgcn_exp2f(x * 1.44269504088896340736f);
}
__device__ __forceinline__ float frcp(float x) { return __builtin_amdgcn_rcpf(x); }
__device__ __forceinline__ float sigm(float x) { return frcp(1.0f + fexp(-x)); }
__device__ __forceinline__ float tanh_fast(float x) {
  return 1.0f - 2.0f * frcp(1.0f + fexp(2.0f * x));
}
__device__ __forceinline__ unsigned short f2bf_rne(float f) {
  union { float f; uint32_t u; } v; v.f = f;
  return (unsigned short)((v.u + 0x7FFFu + ((v.u >> 16) & 1u)) >> 16);
}
__device__ __forceinline__ void gl16(const void* g, void* l) {
  __builtin_amdgcn_global_load_lds(
      (const __attribute__((address_space(1))) unsigned int*)g,
      (__attribute__((address_space(3))) unsigned int*)l, 16, 0, 0);
}
#define VMW(N) asm volatile("s_waitcnt vmcnt(" #N ")" ::: "memory")

// ---- prep: 3 jobs ---------------------------------------------------------
__global__ void prep_all(const float* __restrict__ X, const float* __restrict__ Hin,
                         const float* __restrict__ Wx, const float* __restrict__ Wh,
                         const float* __restrict__ bxp, const float* __restrict__ bhp,
                         unsigned short* __restrict__ ws) {
  const int b = blockIdx.x, tid = threadIdx.x;
  if (b < 8192) {                        // ---- x -> xb[131072][128] ----
    const int t   = b * 256 + tid;
    const int row = t >> 4, k0 = (t & 15) * 8;
    const float* xp = X + (size_t)row * INDIM;
    float4 lo = make_float4(0.f, 0.f, 0.f, 0.f);
    float4 hi = make_float4(0.f, 0.f, 0.f, 0.f);
    if (k0 + 4 <= INDIM) lo = *reinterpret_cast<const float4*>(xp + k0);
    if (k0 + 8 <= INDIM) hi = *reinterpret_cast<const float4*>(xp + k0 + 4);
    float va[8] = {lo.x, lo.y, lo.z, lo.w, hi.x, hi.y, hi.z, hi.w};
    unsigned short o[8];
#pragma unroll
    for (int e = 0; e < 8; ++e) {
      const int k = k0 + e;
      const float f = (k < INDIM) ? va[e] : (k == 127 ? 1.0f : 0.0f);
      o[e] = f2bf_rne(f);
    }
    *reinterpret_cast<bf16x8*>(ws + XB_OFF + (size_t)row * 128 + k0) =
        *reinterpret_cast<bf16x8*>(o);
  } else if (b < 24576) {                // ---- h -> hb[131072][256] ----
    const int t   = (b - 8192) * 256 + tid;
    const int row = t >> 5, k0 = (t & 31) * 8;
    const float* hp = Hin + (size_t)row * HDIM + k0;
    const float4 lo = *reinterpret_cast<const float4*>(hp);
    const float4 hi = *reinterpret_cast<const float4*>(hp + 4);
    unsigned short o[8] = {f2bf_rne(lo.x), f2bf_rne(lo.y), f2bf_rne(lo.z),
                           f2bf_rne(lo.w), f2bf_rne(hi.x), f2bf_rne(hi.y),
                           f2bf_rne(hi.z), f2bf_rne(hi.w)};
    *reinterpret_cast<bf16x8*>(ws + HB_OFF + (size_t)row * 256 + k0) =
        *reinterpret_cast<bf16x8*>(o);
  } else {                               // ---- W -> Bt blob (bias @ k127) --
    const int unit = (b - 24576) * 4 + (tid >> 6);   // 0..767
    const int lane = tid & 63;
    const int kst  = unit % 12;
    const int fidb = unit / 12;
    const int bn   = fidb >> 3, fid = fidb & 7;
    const int g    = fid >> 1,  wc  = fid & 1;
    const int wcol = g * HDIM + bn * 32 + wc * 16 + (lane & 15);
    const int kb   = kst * 32 + (lane >> 4) * 8;
    unsigned short v[8];
#pragma unroll
    for (int e = 0; e < 8; ++e) {
      const int k = kb + e;              // 0..383
      float f = 0.0f;
      if (k < INDIM)     f = Wx[(size_t)k * 1024 + wcol];
      else if (k == 127) f = bxp[wcol] + bhp[wcol];
      else if (k >= 128) f = Wh[(size_t)(k - 128) * 1024 + wcol];
      v[e] = f2bf_rne(f);
    }
    *reinterpret_cast<bf16x8*>(ws + BT_OFF + (size_t)unit * 512 + lane * 8) =
        *reinterpret_cast<bf16x8*>(v);
  }
}

// ---- main -----------------------------------------------------------------
__global__ __launch_bounds__(256, 3)
void lstm_main(const unsigned short* __restrict__ ws,
               const float* __restrict__ Cin, float* __restrict__ out)
{
  __shared__ unsigned char smem[49152];  // 3x(8K A + 8K B)

  const int tid  = threadIdx.x;
  const int orig = blockIdx.x;           // 0..8191 (%8==0 -> bijective)
  const int lg   = ((orig & 7) << 10) | (orig >> 3);
  const int mt   = lg >> 3;              // M tile 0..1023 (128 rows)
  const int bn   = lg & 7;               // N tile 0..7 (32 H-cols)

  const int lane = tid & 63;
  const int l15  = lane & 15;
  const int kq   = lane >> 4;
  const int wid  = tid >> 6;             // 0..3
  const int wr   = wid >> 1;             // 0..1: 64-row group
  const int wc   = wid & 1;              // 0..1: 16-hcol half
  const int ch   = bn * 32 + wc * 16 + l15;
  const int sx   = (l15 >> 1) & 3;       // read-side XOR (== (row>>1)&3)

  const unsigned short* xb = ws + XB_OFF;
  const unsigned short* hb = ws + HB_OFF;
  const unsigned short* Bt = ws + BT_OFF;

  // staging sources: per wave 2 A-units + 2 B-units per stage
  const unsigned short* xsrc[2];
  const unsigned short* hsrc[2];
  const unsigned short* bsrc[2];
#pragma unroll
  for (int j = 0; j < 2; ++j) {
    const int ci  = (wid * 2 + j) * 64 + lane;     // 0..511
    const int r   = ci >> 2;                       // tile row 0..127
    const int sc  = (ci & 3) ^ ((r >> 1) & 3);     // pre-swizzled chunk
    xsrc[j] = xb + (size_t)(mt * 128 + r) * 128 + sc * 8;
    hsrc[j] = hb + (size_t)(mt * 128 + r) * 256 + sc * 8;
    bsrc[j] = Bt + (size_t)((bn * 8 + wid * 2 + j) * 12) * 512 + lane * 8;
  }
  const int au0 = (wid * 2 + 0) * 1024;  // wave-uniform LDS sub-offsets
  const int au1 = (wid * 2 + 1) * 1024;

  f32x4 acc[4][4];
#pragma unroll
  for (int m = 0; m < 4; ++m)
#pragma unroll
    for (int g = 0; g < 4; ++g)
#pragma unroll
      for (int e = 0; e < 4; ++e) acc[m][g][e] = 0.0f;

  float cvv[4][4];

  auto STAGE = [&](int T) {
    char* Ad = (char*)smem + ABUF(T % 3);
    char* Bd = (char*)smem + BBUF(T % 3);
    if (T < 4) {
      gl16(xsrc[0] + T * 32, Ad + au0);
      gl16(xsrc[1] + T * 32, Ad + au1);
    } else {
      gl16(hsrc[0] + (T - 4) * 32, Ad + au0);
      gl16(hsrc[1] + (T - 4) * 32, Ad + au1);
    }
    gl16(bsrc[0] + T * 512, Bd + au0);
    gl16(bsrc[1] + T * 512, Bd + au1);
  };

  auto COMPUTE = [&](int S) {
    const unsigned short* Ab = (const unsigned short*)(smem + ABUF(S % 3));
    const unsigned short* Bb = (const unsigned short*)(smem + BBUF(S % 3));
    bf16x8 afr[4], bfr[4];
#pragma unroll
    for (int m = 0; m < 4; ++m)
      afr[m] = *reinterpret_cast<const bf16x8*>(
          Ab + (wr * 64 + m * 16 + l15) * 32 + ((kq ^ sx) * 8));
#pragma unroll
    for (int g = 0; g < 4; ++g)
      bfr[g] = *reinterpret_cast<const bf16x8*>(
          Bb + (g * 2 + wc) * 512 + lane * 8);
    __builtin_amdgcn_s_setprio(1);
#pragma unroll
    for (int m = 0; m < 4; ++m)
#pragma unroll
      for (int g = 0; g < 4; ++g)
        acc[m][g] = __builtin_amdgcn_mfma_f32_16x16x32_bf16(
            afr[m], bfr[g], acc[m][g], 0, 0, 0);
    __builtin_amdgcn_s_setprio(0);
  };

  // prologue: 2 stages (8 gl_lds) in flight
  STAGE(0);
  STAGE(1);

  // Per-wave vmcnt FIFO (4 gl_lds/stage): at STEP(S), VMW(N) with
  // N = outstanding-after-wait. Steady state: stage S done, S+1 in flight
  // -> N=4. C-prefetch (8 loads) issued at S==9 after STAGE(11):
  // S=10 -> N=4+8=12; S=11 -> N=8 (C only).
#define STEP(S, KN)                                               \
  do {                                                            \
    VMW(KN);                                                      \
    __builtin_amdgcn_s_barrier();                                 \
    if ((S) + 2 < 12) STAGE((S) + 2);                             \
    if ((S) == 9) {                                               \
      const float* cb =                                           \
          Cin + ((size_t)mt * 128 + wr * 64 + kq * 4) * HDIM + ch;\
      _Pragma("unroll")                                           \
      for (int m = 0; m < 4; ++m)                                 \
        _Pragma("unroll")                                         \
        for (int e = 0; e < 4; ++e)                               \
          cvv[m][e] = cb[(size_t)(m * 16 + e) * HDIM];            \
    }                                                             \
    COMPUTE(S);                                                   \
  } while (0)

  STEP(0, 4);  STEP(1, 4);  STEP(2, 4);  STEP(3, 4);
  STEP(4, 4);  STEP(5, 4);  STEP(6, 4);  STEP(7, 4);
  STEP(8, 4);  STEP(9, 4);  STEP(10, 12); STEP(11, 8);
#undef STEP

  // ---- epilogue: bias folded in acc; lane-local gate combine -------------
  float* op  = out + ((size_t)mt * 128 + wr * 64 + kq * 4) * HDIM + ch;
  float* op2 = op + (size_t)NROWS * HDIM;
#pragma unroll
  for (int m = 0; m < 4; ++m) {
#pragma unroll
    for (int e = 0; e < 4; ++e) {
      const float pi = acc[m][0][e];
      const float pf = acc[m][1][e];
      const float pg = acc[m][2][e];
      const float po = acc[m][3][e];
      const float ig = sigm(pi), fg = sigm(pf);
      const float gg = tanh_fast(pg), og = sigm(po);
      const float co = fg * cvv[m][e] + ig * gg;
      const float ho = og * tanh_fast(co);
      op [(size_t)(m * 16 + e) * HDIM] = co;
      op2[(size_t)(m * 16 + e) * HDIM] = ho;
    }
  }
}

extern "C" void kernel_launch(void* const* d_in, const int* in_sizes, int n_in,
                              void* d_out, int out_size, void* d_ws, size_t ws_size,
                              hipStream_t stream) {
  const float* x  = (const float*)d_in[0];
  const float* C  = (const float*)d_in[1];
  const float* h  = (const float*)d_in[2];
  const float* Wx = (const float*)d_in[3];
  const float* Wh = (const float*)d_in[4];
  const float* bx = (const float*)d_in[5];
  const float* bh = (const float*)d_in[6];
  float* o = (float*)d_out;
  unsigned short* ws = (unsigned short*)d_ws;   // ~98 MiB used

  prep_all<<<dim3(24768), dim3(256), 0, stream>>>(x, h, Wx, Wh, bx, bh, ws);
  lstm_main<<<dim3(8192), dim3(256), 0, stream>>>(ws, C, o);
}

// Round 11
// 195.584 us; speedup vs baseline: 2.8439x; 1.0925x over previous
//
#include <hip/hip_runtime.h>
#include <stdint.h>

// ---------------------------------------------------------------------------
// Fused LSTM cell, round 11 = round 10 pipeline, widened to 512thr / 128x256.
//  prep_all: xb[131072][128] bf16 (pad, k127=1.0), hb[131072][256] bf16,
//            Bt fragment blob (bias @ k127). Unchanged.
//  lstm_main: 512 thr (8 waves = 2 wr x 4 wcq), tile 128 rows x 256 gatecols,
//    12 stages BK=32. Per wave per stage: 3 gl_lds (1 A + 2 B, homogeneous
//    FIFO) + 8 ds_read_b128 + 16 MFMA. 3-deep LDS multibuffer (72 KiB) ->
//    2 blocks/CU = 16 waves. Counted vmcnt: VMW(3) steady, VMW(19)/VMW(16)
//    around the 16-load C prefetch, VMW(0) only at the epilogue.
// ---------------------------------------------------------------------------

typedef short bf16x8 __attribute__((ext_vector_type(8)));
typedef float f32x4  __attribute__((ext_vector_type(4)));

#define HDIM   256
#define INDIM  100
#define NROWS  131072
// d_ws layout (ushort offsets): Bt @0 (768 KiB), xb @1 MiB, hb @34 MiB
#define BT_OFF 0
#define XB_OFF (1048576 / 2)
#define HB_OFF (35651584 / 2)
#define ABUF(b) ((b) * 8192)
#define BBUF(b) (24576 + (b) * 16384)

__device__ __forceinline__ float fexp(float x) {
  return __builtin_amdgcn_exp2f(x * 1.44269504088896340736f);
}
__device__ __forceinline__ float frcp(float x) { return __builtin_amdgcn_rcpf(x); }
__device__ __forceinline__ float sigm(float x) { return frcp(1.0f + fexp(-x)); }
__device__ __forceinline__ float tanh_fast(float x) {
  return 1.0f - 2.0f * frcp(1.0f + fexp(2.0f * x));
}
__device__ __forceinline__ unsigned short f2bf_rne(float f) {
  union { float f; uint32_t u; } v; v.f = f;
  return (unsigned short)((v.u + 0x7FFFu + ((v.u >> 16) & 1u)) >> 16);
}
__device__ __forceinline__ void gl16(const void* g, void* l) {
  __builtin_amdgcn_global_load_lds(
      (const __attribute__((address_space(1))) unsigned int*)g,
      (__attribute__((address_space(3))) unsigned int*)l, 16, 0, 0);
}
#define VMW(N) asm volatile("s_waitcnt vmcnt(" #N ")" ::: "memory")

// ---- prep: 3 jobs ---------------------------------------------------------
__global__ void prep_all(const float* __restrict__ X, const float* __restrict__ Hin,
                         const float* __restrict__ Wx, const float* __restrict__ Wh,
                         const float* __restrict__ bxp, const float* __restrict__ bhp,
                         unsigned short* __restrict__ ws) {
  const int b = blockIdx.x, tid = threadIdx.x;
  if (b < 8192) {                        // ---- x -> xb[131072][128] ----
    const int t   = b * 256 + tid;
    const int row = t >> 4, k0 = (t & 15) * 8;
    const float* xp = X + (size_t)row * INDIM;
    float4 lo = make_float4(0.f, 0.f, 0.f, 0.f);
    float4 hi = make_float4(0.f, 0.f, 0.f, 0.f);
    if (k0 + 4 <= INDIM) lo = *reinterpret_cast<const float4*>(xp + k0);
    if (k0 + 8 <= INDIM) hi = *reinterpret_cast<const float4*>(xp + k0 + 4);
    float va[8] = {lo.x, lo.y, lo.z, lo.w, hi.x, hi.y, hi.z, hi.w};
    unsigned short o[8];
#pragma unroll
    for (int e = 0; e < 8; ++e) {
      const int k = k0 + e;
      const float f = (k < INDIM) ? va[e] : (k == 127 ? 1.0f : 0.0f);
      o[e] = f2bf_rne(f);
    }
    *reinterpret_cast<bf16x8*>(ws + XB_OFF + (size_t)row * 128 + k0) =
        *reinterpret_cast<bf16x8*>(o);
  } else if (b < 24576) {                // ---- h -> hb[131072][256] ----
    const int t   = (b - 8192) * 256 + tid;
    const int row = t >> 5, k0 = (t & 31) * 8;
    const float* hp = Hin + (size_t)row * HDIM + k0;
    const float4 lo = *reinterpret_cast<const float4*>(hp);
    const float4 hi = *reinterpret_cast<const float4*>(hp + 4);
    unsigned short o[8] = {f2bf_rne(lo.x), f2bf_rne(lo.y), f2bf_rne(lo.z),
                           f2bf_rne(lo.w), f2bf_rne(hi.x), f2bf_rne(hi.y),
                           f2bf_rne(hi.z), f2bf_rne(hi.w)};
    *reinterpret_cast<bf16x8*>(ws + HB_OFF + (size_t)row * 256 + k0) =
        *reinterpret_cast<bf16x8*>(o);
  } else {                               // ---- W -> Bt blob (bias @ k127) --
    const int unit = (b - 24576) * 4 + (tid >> 6);   // 0..767
    const int lane = tid & 63;
    const int kst  = unit % 12;
    const int fidb = unit / 12;
    const int bn   = fidb >> 3, fid = fidb & 7;
    const int g    = fid >> 1,  wc  = fid & 1;
    const int wcol = g * HDIM + bn * 32 + wc * 16 + (lane & 15);
    const int kb   = kst * 32 + (lane >> 4) * 8;
    unsigned short v[8];
#pragma unroll
    for (int e = 0; e < 8; ++e) {
      const int k = kb + e;              // 0..383
      float f = 0.0f;
      if (k < INDIM)     f = Wx[(size_t)k * 1024 + wcol];
      else if (k == 127) f = bxp[wcol] + bhp[wcol];
      else if (k >= 128) f = Wh[(size_t)(k - 128) * 1024 + wcol];
      v[e] = f2bf_rne(f);
    }
    *reinterpret_cast<bf16x8*>(ws + BT_OFF + (size_t)unit * 512 + lane * 8) =
        *reinterpret_cast<bf16x8*>(v);
  }
}

// ---- main -----------------------------------------------------------------
__global__ __launch_bounds__(512, 2)
void lstm_main(const unsigned short* __restrict__ ws,
               const float* __restrict__ Cin, float* __restrict__ out)
{
  __shared__ unsigned char smem[73728];  // 3 x (8K A + 16K B)

  const int tid  = threadIdx.x;
  const int orig = blockIdx.x;           // 0..4095 (%8==0 -> bijective)
  const int lg   = ((orig & 7) << 9) | (orig >> 3);
  const int mt   = lg >> 2;              // M tile 0..1023 (128 rows)
  const int bnn  = lg & 3;               // N tile 0..3 (64 H-cols)

  const int lane = tid & 63;
  const int l15  = lane & 15;
  const int kq   = lane >> 4;
  const int wid  = tid >> 6;             // 0..7
  const int wr   = wid >> 2;             // 0..1: 64-row group
  const int wcq  = wid & 3;              // 0..3: 16-hcol quarter
  const int ch   = bnn * 64 + wcq * 16 + l15;
  const int sx   = (l15 >> 1) & 3;       // read-side XOR (== (row>>1)&3)

  const unsigned short* xb = ws + XB_OFF;
  const unsigned short* hb = ws + HB_OFF;
  const unsigned short* Bt = ws + BT_OFF;

  // A staging: 1 gl_lds/wave/stage (wave covers rows wid*16..wid*16+15)
  const int ci = wid * 64 + lane;                // 0..511
  const int r  = ci >> 2;                        // tile row 0..127
  const int sc = (ci & 3) ^ ((r >> 1) & 3);      // pre-swizzled chunk
  const unsigned short* xsrc = xb + (size_t)(mt * 128 + r) * 128 + sc * 8;
  const unsigned short* hsrc = hb + (size_t)(mt * 128 + r) * 256 + sc * 8;

  // B staging: 2 gl_lds/wave/stage (units wid*2, wid*2+1 of 16)
  const unsigned short* bsrc[2];
#pragma unroll
  for (int j = 0; j < 2; ++j) {
    const int u  = wid * 2 + j;                  // local unit 0..15
    const int gu = (bnn * 2 + (u >> 3)) * 8 + (u & 7);
    bsrc[j] = Bt + (size_t)gu * 12 * 512 + lane * 8;
  }
  const int adst = wid * 1024;           // wave-uniform LDS sub-offsets
  const int bd0  = (wid * 2 + 0) * 1024;
  const int bd1  = (wid * 2 + 1) * 1024;

  f32x4 acc[4][4];
#pragma unroll
  for (int m = 0; m < 4; ++m)
#pragma unroll
    for (int g = 0; g < 4; ++g)
#pragma unroll
      for (int e = 0; e < 4; ++e) acc[m][g][e] = 0.0f;

  float cvv[4][4];

  auto STAGE = [&](int T) {
    char* Ad = (char*)smem + ABUF(T % 3);
    char* Bd = (char*)smem + BBUF(T % 3);
    if (T < 4) gl16(xsrc + T * 32, Ad + adst);
    else       gl16(hsrc + (T - 4) * 32, Ad + adst);
    gl16(bsrc[0] + T * 512, Bd + bd0);
    gl16(bsrc[1] + T * 512, Bd + bd1);
  };

  auto COMPUTE = [&](int S) {
    const unsigned short* Ab = (const unsigned short*)(smem + ABUF(S % 3));
    const unsigned short* Bb = (const unsigned short*)(smem + BBUF(S % 3));
    bf16x8 afr[4], bfr[4];
#pragma unroll
    for (int m = 0; m < 4; ++m)
      afr[m] = *reinterpret_cast<const bf16x8*>(
          Ab + (wr * 64 + m * 16 + l15) * 32 + ((kq ^ sx) * 8));
#pragma unroll
    for (int g = 0; g < 4; ++g) {
      const int ub = (wcq >> 1) * 8 + g * 2 + (wcq & 1);
      bfr[g] = *reinterpret_cast<const bf16x8*>(Bb + ub * 512 + lane * 8);
    }
    __builtin_amdgcn_s_setprio(1);
#pragma unroll
    for (int m = 0; m < 4; ++m)
#pragma unroll
      for (int g = 0; g < 4; ++g)
        acc[m][g] = __builtin_amdgcn_mfma_f32_16x16x32_bf16(
            afr[m], bfr[g], acc[m][g], 0, 0, 0);
    __builtin_amdgcn_s_setprio(0);
  };

  // prologue: 2 stages (6 gl_lds) in flight
  STAGE(0);
  STAGE(1);

  // FIFO (3 gl_lds/stage/wave): steady VMW(3). C prefetch (16 loads) issued
  // at S==9 after STAGE(11): S=10 -> 3+16=VMW(19); S=11 -> VMW(16).
#define STEP(S, KN)                                               \
  do {                                                            \
    VMW(KN);                                                      \
    __builtin_amdgcn_s_barrier();                                 \
    if ((S) + 2 < 12) STAGE((S) + 2);                             \
    if ((S) == 9) {                                               \
      const float* cb =                                           \
          Cin + ((size_t)mt * 128 + wr * 64 + kq * 4) * HDIM + ch;\
      _Pragma("unroll")                                           \
      for (int m = 0; m < 4; ++m)                                 \
        _Pragma("unroll")                                         \
        for (int e = 0; e < 4; ++e)                               \
          cvv[m][e] = __builtin_nontemporal_load(                 \
              cb + (size_t)(m * 16 + e) * HDIM);                  \
    }                                                             \
    COMPUTE(S);                                                   \
  } while (0)

  STEP(0, 3);  STEP(1, 3);  STEP(2, 3);  STEP(3, 3);
  STEP(4, 3);  STEP(5, 3);  STEP(6, 3);  STEP(7, 3);
  STEP(8, 3);  STEP(9, 3);  STEP(10, 19); STEP(11, 16);
#undef STEP

  VMW(0);                                // C prefetch landed

  // ---- epilogue: bias folded in acc; lane-local gate combine -------------
  float* op  = out + ((size_t)mt * 128 + wr * 64 + kq * 4) * HDIM + ch;
  float* op2 = op + (size_t)NROWS * HDIM;
#pragma unroll
  for (int m = 0; m < 4; ++m) {
#pragma unroll
    for (int e = 0; e < 4; ++e) {
      const float pi = acc[m][0][e];
      const float pf = acc[m][1][e];
      const float pg = acc[m][2][e];
      const float po = acc[m][3][e];
      const float ig = sigm(pi), fg = sigm(pf);
      const float gg = tanh_fast(pg), og = sigm(po);
      const float co = fg * cvv[m][e] + ig * gg;
      const float ho = og * tanh_fast(co);
      __builtin_nontemporal_store(co, op  + (size_t)(m * 16 + e) * HDIM);
      __builtin_nontemporal_store(ho, op2 + (size_t)(m * 16 + e) * HDIM);
    }
  }
}

extern "C" void kernel_launch(void* const* d_in, const int* in_sizes, int n_in,
                              void* d_out, int out_size, void* d_ws, size_t ws_size,
                              hipStream_t stream) {
  const float* x  = (const float*)d_in[0];
  const float* C  = (const float*)d_in[1];
  const float* h  = (const float*)d_in[2];
  const float* Wx = (const float*)d_in[3];
  const float* Wh = (const float*)d_in[4];
  const float* bx = (const float*)d_in[5];
  const float* bh = (const float*)d_in[6];
  float* o = (float*)d_out;
  unsigned short* ws = (unsigned short*)d_ws;   // ~98 MiB used

  prep_all<<<dim3(24768), dim3(256), 0, stream>>>(x, h, Wx, Wh, bx, bh, ws);
  lstm_main<<<dim3(4096), dim3(512), 0, stream>>>(ws, C, o);
}